// Round 4
// baseline (27.261 us; speedup 1.0000x reference)
//
#include <hip/hip_runtime.h>
#include <math.h>

// RandISH: out[b, 2n+0] = Al(deg_n, r_b) * y0_norm[n] * P_l(ct)
//          out[b, 2n+1] = Al * cs[n] * (-1)^deg * Re[(rx + i*ry)^deg]
// rv = vec[b] @ M[n]; rotation preserves |vec|=1 -> no normalization.
// Re[z^d] via 3-term recurrence R_{k+1} = 2x R_k - (x^2+y^2) R_{k-1}.
// Al = exp2(log2e * -0.5*d(d+1)*(r+eps)).
// Thread handles TWO consecutive elements (same b, bases n0 and n0+1)
// -> half the loads/addressing, one 16B nontemporal store.

#define NBASIS 32
#define PLEN 10
#define EPSV 1e-8f
#define LOG2E 1.44269504088896340736f

typedef float f32x4 __attribute__((ext_vector_type(4)));  // clang vector: OK for nontemporal builtin

__global__ __launch_bounds__(256) void randish_kernel(
    const float* __restrict__ vec,        // (B,3)
    const float* __restrict__ rough,      // (B,)
    const float* __restrict__ mats,       // (32,3,3)
    const float* __restrict__ coeffs,     // (32,10) increasing power
    const float* __restrict__ cscale,     // (32,)
    const float* __restrict__ y0n,        // (32,)
    const int*   __restrict__ degs,       // (32,)
    float* __restrict__ out,              // (B,64)
    int npairs)                           // B*16
{
    const int tid = blockIdx.x * blockDim.x + threadIdx.x;
    const int stride = gridDim.x * blockDim.x;   // multiple of 16 -> n0 invariant
    const int n0 = (2 * tid) & 31;               // even base index; slot s -> n0+s

    // ---- per-n constants for both slots (loop-invariant) ----
    float m[2][9], h[2][5], cs[2], c2[2], c2e[2];
    int dg[2], par[2];
#pragma unroll
    for (int s = 0; s < 2; ++s) {
        const int n = n0 + s;
#pragma unroll
        for (int j = 0; j < 9; ++j) m[s][j] = mats[n * 9 + j];
        const int d = degs[n];
        dg[s] = d;
        const int pr = d & 1;
        par[s] = pr;
        const float yn = y0n[n];                 // fold y0_norm into Horner coeffs
#pragma unroll
        for (int k = 0; k < 5; ++k) {
            const int idx = pr + 2 * k;          // parity-compressed Legendre
            h[s][k] = (idx < PLEN) ? coeffs[n * PLEN + idx] * yn : 0.0f;
        }
        float c = cscale[n];
        if (pr) c = -c;                          // fold (-1)^deg
        cs[s] = c;
        const float negc = -0.5f * (float)(d * (d + 1)) * LOG2E;
        c2[s]  = negc;
        c2e[s] = negc * EPSV;
    }

    for (int p = tid; p < npairs; p += stride) {
        const int b = p >> 4;
        const float v0 = vec[b * 3 + 0];
        const float v1 = vec[b * 3 + 1];
        const float v2 = vec[b * 3 + 2];
        const float r  = rough[b];

        f32x4 o;
#pragma unroll
        for (int s = 0; s < 2; ++s) {
            // rotate (|rv| == 1)
            const float xh = fmaf(v0, m[s][0], fmaf(v1, m[s][3], v2 * m[s][6]));
            const float yh = fmaf(v0, m[s][1], fmaf(v1, m[s][4], v2 * m[s][7]));
            const float ct = fmaf(v0, m[s][2], fmaf(v1, m[s][5], v2 * m[s][8]));

            // Legendre: v = ct^par * H(ct^2)  (y0_norm pre-folded)
            const float ct2 = ct * ct;
            float v = h[s][4];
            v = fmaf(v, ct2, h[s][3]);
            v = fmaf(v, ct2, h[s][2]);
            v = fmaf(v, ct2, h[s][1]);
            v = fmaf(v, ct2, h[s][0]);
            v = par[s] ? v * ct : v;             // mask hoisted (par invariant)

            // Re[(xh+i*yh)^deg] via 3-term recurrence, d in [1,9]
            const float ss  = fmaf(yh, yh, xh * xh);
            const float m2x = xh + xh;
            float Rm2 = 1.0f;                    // R_0
            float Rm1 = xh;                      // R_1
            float res = xh;                      // deg==1 default
#pragma unroll
            for (int k = 2; k <= 9; ++k) {
                const float Rk = fmaf(m2x, Rm1, -(ss * Rm2));
                res = (dg[s] == k) ? Rk : res;   // cmp hoisted (dg invariant)
                Rm2 = Rm1;
                Rm1 = Rk;
            }
            const float yl1 = cs[s] * res;

            // Al = exp2(c2*(r+eps))
            const float al = __builtin_amdgcn_exp2f(fmaf(r, c2[s], c2e[s]));

            o[2 * s + 0] = al * v;
            o[2 * s + 1] = al * yl1;
        }
        __builtin_nontemporal_store(o, reinterpret_cast<f32x4*>(out) + p);
    }
}

extern "C" void kernel_launch(void* const* d_in, const int* in_sizes, int n_in,
                              void* d_out, int out_size, void* d_ws, size_t ws_size,
                              hipStream_t stream) {
    const float* vec    = (const float*)d_in[0];
    const float* rough  = (const float*)d_in[1];
    const float* mats   = (const float*)d_in[2];
    const float* coeffs = (const float*)d_in[3];
    const float* cscale = (const float*)d_in[4];
    const float* y0n    = (const float*)d_in[5];
    const int*   degs   = (const int*)d_in[6];
    float* out = (float*)d_out;

    const int B = in_sizes[1];              // roughness element count
    const int npairs = B * (NBASIS / 2);    // one thread per 2 consecutive outputs

    const int block = 256;
    int grid = (npairs + block - 1) / block;
    if (grid > 4096) grid = 4096;           // grid-stride the rest

    randish_kernel<<<grid, block, 0, stream>>>(vec, rough, mats, coeffs, cscale,
                                               y0n, degs, out, npairs);
}